// Round 13
// baseline (1604.578 us; speedup 1.0000x reference)
//
#include <hip/hip_runtime.h>
#include <hip/hip_fp16.h>
#include <cstdio>

// EmbeddingCellLSTM: B=32, S=2048, IN=64, EMB=32, H=256, 4H=1024
//  prep_kernel : blocks 0..1023 = zx tile (f16 MFMA, r10 verified); blocks 1024..1039 = W_hh
//                i8 pack (interleaved unit/gate cols). Merged so pack overlaps zx.
//  lstm_kernel : transposed i8 MFMA structure (r9/r10 verified) with the per-step s_barrier
//                REPLACED by per-chunk producer/consumer LDS flags:
//                  - h-chunk c (units 64c..64c+64) is produced by waves 4c..4c+3 only;
//                  - producer: ds_write h, lgkmcnt(0), lane0 ds_atomic_add flags[w>>2];
//                  - consumer: spin flags[c] >= 4s+4 (acquire) just before bq chunk-c read,
//                    interleaved into the chunk-major MFMA accumulate;
//                  - prio 3-(w>>2): chunk-0 producers finish first -> relay pipeline.
//                Safety: program order (reads before writes per wave) + monotonic counters
//                transitively gate reads -> 2 h-buffers suffice; no deadlock (waits only on
//                prior-step signals). r10 diagnosis: barrier re-sync forced 4 tails/SIMD to
//                serialize post-MFMA (VALU 760 cyc, only 170 overlapped); flags let wave skew
//                persist so tails hide under other waves' MFMA phases.
//  Locked-in: matrix pipe = 1024 cyc/step/SIMD (r4-r10, 7x) = i8 dense peak. k3 floor =
//  1024 + dependent chain (~350). MX-fp8 slower; M/N/K repacking can't cut MFMA count.
//  [Round 12: fix compile error only — missing (const v4i*) cast at lstm_kernel launch.]

#define WPK_OFF (134217728u)   // zx = 32*2048*1024*2 bytes, then wpk 256 KB

typedef int v4i __attribute__((ext_vector_type(4)));
typedef _Float16 v8h __attribute__((ext_vector_type(8)));
typedef float f32x4 __attribute__((ext_vector_type(4)));

static __device__ __forceinline__ unsigned short f16bits(float v) {
  _Float16 h = (_Float16)v;
  return __builtin_bit_cast(unsigned short, h);
}

static __device__ __forceinline__ float h2f(unsigned short b) {
  return (float)__builtin_bit_cast(_Float16, b);
}

// quad_perm broadcast of lane g (0..3) within each aligned 4-lane quad
#define QBCAST(x, g) __builtin_amdgcn_mov_dpp((x), (g) * 0x55, 0xF, 0xF, false)

// ---------------- prep: zx GEMM (blocks 0..1023) + W_hh pack (blocks 1024..1039) ----------------
// zx path: block = 64-row stripe; XeT[64][100] fp16 staged once; WT per col-tile; 3x
// mfma_f32_16x16x32_f16 per 16x16 out tile; [100] pad -> conflict-free.
// pack path: tile = tr*4+kc; thread t (4 per 256-thr block via j-loop): w=t>>6, m=lane&15,
// q=lane>>4; col m -> W row (m&3)*256 + w*16 + tr*4 + (m>>2); byte j = W[row][kc*64+q*16+j];
// wq = rint(w*2032), |w|<1/16 -> |wq|<=127.
__global__ __launch_bounds__(256) void prep_kernel(const float* __restrict__ x,
                                                   const float* __restrict__ emb,
                                                   const float* __restrict__ Wih,
                                                   const float* __restrict__ bias,
                                                   const float* __restrict__ Whh,
                                                   unsigned short* __restrict__ zx,
                                                   uint4* __restrict__ wpk) {
  int blk = blockIdx.x;
  int tid = threadIdx.x;
  if (blk >= 1024) {
    int tile = blk - 1024;          // 0..15
    int tr = tile >> 2, kc = tile & 3;
#pragma unroll
    for (int j = 0; j < 4; j++) {
      int t = tid + j * 256;
      int w = t >> 6, lane = t & 63, m = lane & 15, q = lane >> 4;
      int row = (m & 3) * 256 + w * 16 + tr * 4 + (m >> 2);
      const float* src = Whh + row * 256 + kc * 64 + q * 16;
      unsigned int pk[4];
#pragma unroll
      for (int d = 0; d < 4; d++) {
        unsigned int v = 0;
#pragma unroll
        for (int e = 0; e < 4; e++) {
          int qv = (int)rintf(src[d * 4 + e] * 2032.0f);
          v |= ((unsigned int)(qv & 255)) << (8 * e);
        }
        pk[d] = v;
      }
      uint4 o; o.x = pk[0]; o.y = pk[1]; o.z = pk[2]; o.w = pk[3];
      wpk[tile * 1024 + t] = o;
    }
    return;
  }

  __shared__ __align__(16) _Float16 XeT[64][100];
  __shared__ __align__(16) _Float16 WT[64][100];
  int m0 = blk * 64;
  for (int idx = tid; idx < 6144; idx += 256) {
    int r = idx / 96, k = idx - r * 96;
    size_t m = (size_t)(m0 + r);
    float v = (k < 64) ? x[m * 64 + k] : emb[m * 32 + (k - 64)];
    XeT[r][k] = (_Float16)v;
  }
  __syncthreads();

  int ww = tid >> 6, lane = tid & 63, qq = lane >> 4, nl = lane & 15;
  v8h af[3];
#pragma unroll
  for (int kc = 0; kc < 3; kc++)
    af[kc] = *(const v8h*)&XeT[ww * 16 + nl][kc * 32 + qq * 8];

  for (int nt = 0; nt < 16; nt++) {
    int n0 = nt * 64;
    __syncthreads();                // protect WT vs previous iter's readers
    for (int idx = tid; idx < 6144; idx += 256) {
      int c = idx / 96, k = idx - c * 96;
      WT[c][k] = (_Float16)Wih[(size_t)(n0 + c) * 96 + k];
    }
    __syncthreads();
#pragma unroll
    for (int nn = 0; nn < 4; nn++) {
      f32x4 acc = {0.f, 0.f, 0.f, 0.f};
#pragma unroll
      for (int kc = 0; kc < 3; kc++) {
        v8h bf = *(const v8h*)&WT[nn * 16 + nl][kc * 32 + qq * 8];
        acc = __builtin_amdgcn_mfma_f32_16x16x32_f16(af[kc], bf, acc, 0, 0, 0);
      }
      int col = n0 + nn * 16 + nl;
      float bv = bias[col];
#pragma unroll
      for (int r = 0; r < 4; r++) {
        size_t m = (size_t)(m0 + ww * 16 + qq * 4 + r);
        zx[m * 1024 + (size_t)col] = f16bits(acc[r] + bv);
      }
    }
  }
}

// ---------------- k3: persistent per-batch LSTM (transposed i8 MFMA, flag sync) ----------------
__global__ __launch_bounds__(1024, 4) void lstm_kernel(const unsigned short* __restrict__ zx,
                                                       const v4i* __restrict__ wpk,
                                                       float* __restrict__ out) {
  __shared__ __align__(16) char hq[2][256];
  __shared__ int flags[4];
  const int t = threadIdx.x, b = blockIdx.x;
  const int w = t >> 6, lane = t & 63, q = lane >> 4, n = lane & 15;

  // full W_hh residency: 16 frags x 16B i8 = 64 regs (B-operand; AGPR-friendly)
  v4i wf[16];
#pragma unroll
  for (int i = 0; i < 16; i++) wf[i] = wpk[i * 1024 + t];

  if (t < 128) ((unsigned int*)hq)[t] = 0;   // zero both h buffers (2x256 i8)
  if (t == 0) { flags[0] = 4; flags[1] = 4; flags[2] = 4; flags[3] = 4; }  // "step -1 done"
  __syncthreads();

  // chunk-relay prio: chunk-c producer group (waves 4c..4c+3) at prio 3-c.
  const int pr = 3 - (w >> 2);

  const float dq = 1.0f / (2032.0f * 127.0f);
  const int g = n & 3;                            // this lane's gate
  const int u = w * 16 + q * 4 + (n >> 2);        // this lane's unit
  const bool isg = (g == 2);                      // gate 2 is tanh
  const float sc = isg ? 2.88539008f : 1.44269504f;
  const unsigned short* zp = zx + (size_t)b * (2048u * 1024u) + (unsigned)(g * 256 + u);
  const bool wr = (g == 0);                       // quad lane 0 writes
  float* op = out + (size_t)b * (2048u * 256u) + u;
  char* hw0 = &hq[1][u];                          // written in even steps (for s+1)
  char* hw1 = &hq[0][u];                          // written in odd steps
  const int myflag = w >> 2;                      // chunk this wave produces
  const v4i zerov = {0, 0, 0, 0};                 // persistent MFMA C operand (D != C)

  float cst = 0.f, hlast = 0.f;
  unsigned short za = zp[0];                      // zx for even step s
  unsigned short zb = zp[1024];                   // zx for odd step s+1

#define WAITCHUNK(C, TGT)                                                             \
  while (__hip_atomic_load(&flags[C], __ATOMIC_ACQUIRE, __HIP_MEMORY_SCOPE_WORKGROUP) \
         < (TGT)) {}                                                                  \
  asm volatile("" ::: "memory");

#define LSTM_STEP(HC, HWPTR, ZREG, SIDX, TGT)                                         \
  {                                                                                   \
    unsigned short zu = ZREG;                                                         \
    ZREG = zp[(size_t)((SIDX) + 2) << 10];  /* distance-2 prefetch; tail OOB-safe */  \
    const char* hc = (HC);                                                            \
    if (pr == 3) __builtin_amdgcn_s_setprio(3);                                       \
    else if (pr == 2) __builtin_amdgcn_s_setprio(2);                                  \
    else if (pr == 1) __builtin_amdgcn_s_setprio(1);                                  \
    v4i acc[4];                                                                       \
    {                                                                                 \
      WAITCHUNK(0, TGT)                                                               \
      v4i bq = *(const v4i*)(hc + 0 * 64 + q * 16);                                   \
      _Pragma("unroll")                                                               \
      for (int tt = 0; tt < 4; tt++)                                                  \
        acc[tt] = __builtin_amdgcn_mfma_i32_16x16x64_i8(bq, wf[tt * 4 + 0], zerov, 0, 0, 0); \
    }                                                                                 \
    {                                                                                 \
      WAITCHUNK(1, TGT)                                                               \
      v4i bq = *(const v4i*)(hc + 1 * 64 + q * 16);                                   \
      _Pragma("unroll")                                                               \
      for (int tt = 0; tt < 4; tt++)                                                  \
        acc[tt] = __builtin_amdgcn_mfma_i32_16x16x64_i8(bq, wf[tt * 4 + 1], acc[tt], 0, 0, 0); \
    }                                                                                 \
    {                                                                                 \
      WAITCHUNK(2, TGT)                                                               \
      v4i bq = *(const v4i*)(hc + 2 * 64 + q * 16);                                   \
      _Pragma("unroll")                                                               \
      for (int tt = 0; tt < 4; tt++)                                                  \
        acc[tt] = __builtin_amdgcn_mfma_i32_16x16x64_i8(bq, wf[tt * 4 + 2], acc[tt], 0, 0, 0); \
    }                                                                                 \
    {                                                                                 \
      WAITCHUNK(3, TGT)                                                               \
      v4i bq = *(const v4i*)(hc + 3 * 64 + q * 16);                                   \
      _Pragma("unroll")                                                               \
      for (int tt = 0; tt < 4; tt++)                                                  \
        acc[tt] = __builtin_amdgcn_mfma_i32_16x16x64_i8(bq, wf[tt * 4 + 3], acc[tt], 0, 0, 0); \
    }                                                                                 \
    __builtin_amdgcn_s_setprio(0);                                                    \
    int tlo = (q & 1) ? acc[1][0] : acc[0][0];                                        \
    int thi = (q & 1) ? acc[3][0] : acc[2][0];                                        \
    int zi  = (q & 2) ? thi : tlo;                                                    \
    float z = (float)zi * dq + h2f(zu);                                               \
    float e = __builtin_amdgcn_exp2f(-sc * z);                                        \
    float r = __builtin_amdgcn_rcpf(1.f + e);                                         \
    float a = isg ? (2.f * r - 1.f) : r;                                              \
    int ab = __builtin_bit_cast(int, a);                                              \
    float ai = __builtin_bit_cast(float, QBCAST(ab, 0));                              \
    float af = __builtin_bit_cast(float, QBCAST(ab, 1));                              \
    float ag = __builtin_bit_cast(float, QBCAST(ab, 2));                              \
    float ao = __builtin_bit_cast(float, QBCAST(ab, 3));                              \
    float cn = af * cst + ai * ag;                                                    \
    float e2 = __builtin_amdgcn_exp2f(-2.88539008f * cn);                             \
    float th = 2.f * __builtin_amdgcn_rcpf(1.f + e2) - 1.f;                           \
    float h = ao * th;                                                                \
    cst = cn;                                                                         \
    hlast = h;                                                                        \
    if (wr) {                                                                         \
      float fr = __builtin_fmaf(h, 127.0f, 12582912.0f);                              \
      int iq = __builtin_bit_cast(int, fr) - 0x4B400000;                              \
      *(HWPTR) = (char)iq;                                                            \
    }                                                                                 \
    asm volatile("s_waitcnt lgkmcnt(0)" ::: "memory");                                \
    if (lane == 0)                                                                    \
      __hip_atomic_fetch_add(&flags[myflag], 1, __ATOMIC_RELEASE,                     \
                             __HIP_MEMORY_SCOPE_WORKGROUP);                           \
    if (wr) op[(size_t)(SIDX) * 256] = h;                                             \
  }

  for (int s = 0; s < 2048; s += 2) {
    LSTM_STEP(hq[0], hw0, za, s, 4 * s + 4)       // even: read buf0, write buf1
    LSTM_STEP(hq[1], hw1, zb, s + 1, 4 * s + 8)   // odd : read buf1, write buf0
  }
#undef LSTM_STEP
#undef WAITCHUNK

  if (wr) {
    out[16777216u + (size_t)b * 256 + u] = hlast;          // final h
    out[16777216u + 8192u + (size_t)b * 256 + u] = cst;    // final c
  }
}

extern "C" void kernel_launch(void* const* d_in, const int* in_sizes, int n_in,
                              void* d_out, int out_size, void* d_ws, size_t ws_size,
                              hipStream_t stream) {
  const float* x = (const float*)d_in[0];
  const float* emb = (const float*)d_in[1];
  const float* W_ih = (const float*)d_in[2];
  const float* W_hh = (const float*)d_in[3];
  const float* bias = (const float*)d_in[4];
  float* out = (float*)d_out;
  char* ws = (char*)d_ws;

  unsigned short* zx = (unsigned short*)ws;
  uint4* wpk = (uint4*)(ws + WPK_OFF);

  size_t need = (size_t)WPK_OFF + 262144u;
  if (ws_size < need) {
    fprintf(stderr, "kernel_launch: ws too small: %zu < %zu\n", ws_size, need);
  }

  prep_kernel<<<dim3(1040), dim3(256), 0, stream>>>(x, emb, W_ih, bias, W_hh, zx, wpk);
  lstm_kernel<<<dim3(32), dim3(1024), 0, stream>>>(zx, (const v4i*)wpk, out);
}

// Round 18
// 1521.187 us; speedup vs baseline: 1.0548x; 1.0548x over previous
//
#include <hip/hip_runtime.h>
#include <hip/hip_fp16.h>
#include <cstdio>

// EmbeddingCellLSTM: B=32, S=2048, IN=64, EMB=32, H=256, 4H=1024
//  prep_kernel : blocks 0..4095 = zx tiles SPLIT 4-way: block (mt, ntq) stages Xe[64][96] once
//                and computes 4 col-tiles (was 16 serial tiles/block -> latency-exposed ~100us;
//                4x parallelism -> ~50-60us, near BW floor). Blocks 4096..4111 = W_hh i8 pack.
//  lstm_kernel : r10's measured optimum (1381us): transposed i8 MFMA, dpp quad gather, lean
//                "lgkmcnt(0); s_barrier" sync, 2x unroll, distance-2 zx prefetch, wave-prio
//                stagger 3,2,1,0 on the MFMA cluster, magic-rounding h quant.
//  Sync-structure ledger (all measured): per-step full convergence is MANDATORY-CHEAPEST —
//    r8 (2 batches/CU): floor scales with batches/CU -> 2048+tail, REFUTED (2694us);
//    r13 (per-chunk flag relay): spins break MFMA issue stream, REFUTED (1465us);
//    r10 (single lean barrier): 1381us = best. k3 floor = 1024 cyc matrix (i8 dense peak,
//    8 rounds consistent) + ~590 exposure (dependent tail + barrier turnaround).
//  [Round 17: resubmission — r13 kernel still unmeasured (r14/r16/r17 GPU timeout, r15 container).]

#define WPK_OFF (134217728u)   // zx = 32*2048*1024*2 bytes, then wpk 256 KB

typedef int v4i __attribute__((ext_vector_type(4)));
typedef _Float16 v8h __attribute__((ext_vector_type(8)));
typedef float f32x4 __attribute__((ext_vector_type(4)));

static __device__ __forceinline__ unsigned short f16bits(float v) {
  _Float16 h = (_Float16)v;
  return __builtin_bit_cast(unsigned short, h);
}

static __device__ __forceinline__ float h2f(unsigned short b) {
  return (float)__builtin_bit_cast(_Float16, b);
}

// quad_perm broadcast of lane g (0..3) within each aligned 4-lane quad
#define QBCAST(x, g) __builtin_amdgcn_mov_dpp((x), (g) * 0x55, 0xF, 0xF, false)

// ---------------- prep: zx GEMM (blocks 0..4095, 4-way nt split) + W_hh pack (4096..4111) ----------------
// zx path: block = (m-stripe mt = blk>>2, nt-quarter = blk&3). XeT[64][100] fp16 staged once;
// WT per col-tile; 3x mfma_f32_16x16x32_f16 per 16x16 out tile; [100] pad -> conflict-free.
// pack path: tile = tr*4+kc; col m -> W row (m&3)*256 + w*16 + tr*4 + (m>>2) (gate m&3,
// unit w*16+tr*4+(m>>2)); byte j = W[row][kc*64+q*16+j]; wq = rint(w*2032) -> |wq|<=127.
__global__ __launch_bounds__(256) void prep_kernel(const float* __restrict__ x,
                                                   const float* __restrict__ emb,
                                                   const float* __restrict__ Wih,
                                                   const float* __restrict__ bias,
                                                   const float* __restrict__ Whh,
                                                   unsigned short* __restrict__ zx,
                                                   uint4* __restrict__ wpk) {
  int blk = blockIdx.x;
  int tid = threadIdx.x;
  if (blk >= 4096) {
    int tile = blk - 4096;          // 0..15
    int tr = tile >> 2, kc = tile & 3;
#pragma unroll
    for (int j = 0; j < 4; j++) {
      int t = tid + j * 256;
      int w = t >> 6, lane = t & 63, m = lane & 15, q = lane >> 4;
      int row = (m & 3) * 256 + w * 16 + tr * 4 + (m >> 2);
      const float* src = Whh + row * 256 + kc * 64 + q * 16;
      unsigned int pk[4];
#pragma unroll
      for (int d = 0; d < 4; d++) {
        unsigned int v = 0;
#pragma unroll
        for (int e = 0; e < 4; e++) {
          int qv = (int)rintf(src[d * 4 + e] * 2032.0f);
          v |= ((unsigned int)(qv & 255)) << (8 * e);
        }
        pk[d] = v;
      }
      uint4 o; o.x = pk[0]; o.y = pk[1]; o.z = pk[2]; o.w = pk[3];
      wpk[tile * 1024 + t] = o;
    }
    return;
  }

  __shared__ __align__(16) _Float16 XeT[64][100];
  __shared__ __align__(16) _Float16 WT[64][100];
  int mt = blk >> 2, ntq = blk & 3;
  int m0 = mt * 64;
  for (int idx = tid; idx < 6144; idx += 256) {
    int r = idx / 96, k = idx - r * 96;
    size_t m = (size_t)(m0 + r);
    float v = (k < 64) ? x[m * 64 + k] : emb[m * 32 + (k - 64)];
    XeT[r][k] = (_Float16)v;
  }
  __syncthreads();

  int ww = tid >> 6, lane = tid & 63, qq = lane >> 4, nl = lane & 15;
  v8h af[3];
#pragma unroll
  for (int kc = 0; kc < 3; kc++)
    af[kc] = *(const v8h*)&XeT[ww * 16 + nl][kc * 32 + qq * 8];

  for (int nt = ntq * 4; nt < ntq * 4 + 4; nt++) {
    int n0 = nt * 64;
    __syncthreads();                // protect WT vs previous iter's readers
    for (int idx = tid; idx < 6144; idx += 256) {
      int c = idx / 96, k = idx - c * 96;
      WT[c][k] = (_Float16)Wih[(size_t)(n0 + c) * 96 + k];
    }
    __syncthreads();
#pragma unroll
    for (int nn = 0; nn < 4; nn++) {
      f32x4 acc = {0.f, 0.f, 0.f, 0.f};
#pragma unroll
      for (int kc = 0; kc < 3; kc++) {
        v8h bf = *(const v8h*)&WT[nn * 16 + nl][kc * 32 + qq * 8];
        acc = __builtin_amdgcn_mfma_f32_16x16x32_f16(af[kc], bf, acc, 0, 0, 0);
      }
      int col = n0 + nn * 16 + nl;
      float bv = bias[col];
#pragma unroll
      for (int r = 0; r < 4; r++) {
        size_t m = (size_t)(m0 + ww * 16 + qq * 4 + r);
        zx[m * 1024 + (size_t)col] = f16bits(acc[r] + bv);
      }
    }
  }
}

// ---------------- k3: persistent per-batch LSTM (transposed i8 MFMA, dpp gather) ----------------
// r10 verified optimum: 32 blocks (1/batch) x 16 waves; W register-resident (16x 16B i8 frags);
// per step: 4 bq ds_reads, 16 MFMAs (chunk-major), 3-cndmask select, ONE activation/lane,
// quad_perm gate gather, c/h update, g==0 writes i8 h + fp32 out; lean lgkmcnt-only barrier.
__global__ __launch_bounds__(1024, 4) void lstm_kernel(const unsigned short* __restrict__ zx,
                                                       const v4i* __restrict__ wpk,
                                                       float* __restrict__ out) {
  __shared__ __align__(16) char hq[2][256];
  const int t = threadIdx.x, b = blockIdx.x;
  const int w = t >> 6, lane = t & 63, q = lane >> 4, n = lane & 15;

  // full W_hh residency: 16 frags x 16B i8 = 64 regs (B-operand; AGPR-friendly)
  v4i wf[16];
#pragma unroll
  for (int i = 0; i < 16; i++) wf[i] = wpk[i * 1024 + t];

  if (t < 128) ((unsigned int*)hq)[t] = 0;   // zero both h buffers (2x256 i8)
  __syncthreads();

  // static stagger prio for the MFMA phase (robust to either wave->SIMD map)
  const int pr = 3 - (((w >> 2) ^ w) & 3);

  const float dq = 1.0f / (2032.0f * 127.0f);
  const int g = n & 3;                            // this lane's gate
  const int u = w * 16 + q * 4 + (n >> 2);        // this lane's unit
  const bool isg = (g == 2);                      // gate 2 is tanh
  const float sc = isg ? 2.88539008f : 1.44269504f;
  const unsigned short* zp = zx + (size_t)b * (2048u * 1024u) + (unsigned)(g * 256 + u);
  const bool wr = (g == 0);                       // quad lane 0 writes
  float* op = out + (size_t)b * (2048u * 256u) + u;
  char* hw0 = &hq[1][u];                          // written in even steps (for s+1)
  char* hw1 = &hq[0][u];                          // written in odd steps
  const v4i zerov = {0, 0, 0, 0};                 // persistent MFMA C operand (D != C)

  float cst = 0.f, hlast = 0.f;
  unsigned short za = zp[0];                      // zx for even step s
  unsigned short zb = zp[1024];                   // zx for odd step s+1

#define LSTM_STEP(HC, HWPTR, ZREG, SIDX)                                              \
  {                                                                                   \
    unsigned short zu = ZREG;                                                         \
    ZREG = zp[(size_t)((SIDX) + 2) << 10];  /* global prefetch FIRST (indep of LDS) */\
    const char* hc = (HC);                                                            \
    v4i bq[4];                                                                        \
    _Pragma("unroll")                                                                 \
    for (int c = 0; c < 4; c++) bq[c] = *(const v4i*)(hc + c * 64 + q * 16);          \
    if (pr == 3) __builtin_amdgcn_s_setprio(3);                                       \
    else if (pr == 2) __builtin_amdgcn_s_setprio(2);                                  \
    else if (pr == 1) __builtin_amdgcn_s_setprio(1);                                  \
    v4i acc[4];                                                                       \
    _Pragma("unroll")                                                                 \
    for (int tt = 0; tt < 4; tt++)                                                    \
      acc[tt] = __builtin_amdgcn_mfma_i32_16x16x64_i8(bq[0], wf[tt * 4 + 0], zerov, 0, 0, 0); \
    _Pragma("unroll")                                                                 \
    for (int c = 1; c < 4; c++)                                                       \
      _Pragma("unroll")                                                               \
      for (int tt = 0; tt < 4; tt++)                                                  \
        acc[tt] = __builtin_amdgcn_mfma_i32_16x16x64_i8(bq[c], wf[tt * 4 + c], acc[tt], 0, 0, 0); \
    __builtin_amdgcn_s_setprio(0);                                                    \
    int tlo = (q & 1) ? acc[1][0] : acc[0][0];                                        \
    int thi = (q & 1) ? acc[3][0] : acc[2][0];                                        \
    int zi  = (q & 2) ? thi : tlo;                                                    \
    float z = (float)zi * dq + h2f(zu);                                               \
    float e = __builtin_amdgcn_exp2f(-sc * z);                                        \
    float r = __builtin_amdgcn_rcpf(1.f + e);                                         \
    float a = isg ? (2.f * r - 1.f) : r;                                              \
    int ab = __builtin_bit_cast(int, a);                                              \
    float ai = __builtin_bit_cast(float, QBCAST(ab, 0));                              \
    float af = __builtin_bit_cast(float, QBCAST(ab, 1));                              \
    float ag = __builtin_bit_cast(float, QBCAST(ab, 2));                              \
    float ao = __builtin_bit_cast(float, QBCAST(ab, 3));                              \
    float cn = af * cst + ai * ag;                                                    \
    float e2 = __builtin_amdgcn_exp2f(-2.88539008f * cn);                             \
    float th = 2.f * __builtin_amdgcn_rcpf(1.f + e2) - 1.f;                           \
    float h = ao * th;                                                                \
    cst = cn;                                                                         \
    hlast = h;                                                                        \
    if (wr) {                                                                         \
      /* magic rounding: fma into 1.5*2^23 -> mantissa low bits = rint(h*127) */      \
      float fr = __builtin_fmaf(h, 127.0f, 12582912.0f);                              \
      int iq = __builtin_bit_cast(int, fr) - 0x4B400000;                              \
      *(HWPTR) = (char)iq;                                                            \
      op[(size_t)(SIDX) * 256] = h;                                                   \
    }                                                                                 \
    asm volatile("s_waitcnt lgkmcnt(0)\n\ts_barrier" ::: "memory");                   \
  }

  for (int s = 0; s < 2048; s += 2) {
    LSTM_STEP(hq[0], hw0, za, s)       // even: read buf0, write buf1
    LSTM_STEP(hq[1], hw1, zb, s + 1)   // odd : read buf1, write buf0
  }
#undef LSTM_STEP

  if (wr) {
    out[16777216u + (size_t)b * 256 + u] = hlast;          // final h
    out[16777216u + 8192u + (size_t)b * 256 + u] = cst;    // final c
  }
}

extern "C" void kernel_launch(void* const* d_in, const int* in_sizes, int n_in,
                              void* d_out, int out_size, void* d_ws, size_t ws_size,
                              hipStream_t stream) {
  const float* x = (const float*)d_in[0];
  const float* emb = (const float*)d_in[1];
  const float* W_ih = (const float*)d_in[2];
  const float* W_hh = (const float*)d_in[3];
  const float* bias = (const float*)d_in[4];
  float* out = (float*)d_out;
  char* ws = (char*)d_ws;

  unsigned short* zx = (unsigned short*)ws;
  uint4* wpk = (uint4*)(ws + WPK_OFF);

  size_t need = (size_t)WPK_OFF + 262144u;
  if (ws_size < need) {
    fprintf(stderr, "kernel_launch: ws too small: %zu < %zu\n", ws_size, need);
  }

  prep_kernel<<<dim3(4112), dim3(256), 0, stream>>>(x, emb, W_ih, bias, W_hh, zx, wpk);
  lstm_kernel<<<dim3(32), dim3(1024), 0, stream>>>(zx, (const v4i*)wpk, out);
}